// Round 3
// baseline (504.872 us; speedup 1.0000x reference)
//
#include <hip/hip_runtime.h>
#include <hip/hip_bf16.h>
#include <math.h>

typedef __bf16 bf16x8 __attribute__((ext_vector_type(8)));
typedef float f32x4 __attribute__((ext_vector_type(4)));
typedef unsigned short u16x8 __attribute__((ext_vector_type(8)));

#define DEV __device__ __forceinline__

DEV unsigned short f2bf(float f){ __hip_bfloat16 h=__float2bfloat16(f); unsigned short u; __builtin_memcpy(&u,&h,2); return u; }
DEV float bf2f(unsigned short u){ __hip_bfloat16 h; __builtin_memcpy(&h,&u,2); return __bfloat162float(h); }

// tanh-form GELU: exp is HW (v_exp_f32), rcp is HW.
DEV float gelu_f(float v){
  float u = v*(0.7978845608f + 0.0356774081f*v*v);
  float e = __expf(2.0f*u);
  float t = 1.0f - 2.0f*__builtin_amdgcn_rcpf(e + 1.0f);
  return 0.5f*v*(1.0f + t);
}

DEV void gl2lds16(const void* g, void* l){
  __builtin_amdgcn_global_load_lds((const __attribute__((address_space(1))) void*)g,
                                   (__attribute__((address_space(3))) void*)l, 16, 0, 0);
}

// ---- weight transpose: WT[n][k] (bf16) = W[k][n] (f32)
__global__ __launch_bounds__(256) void k_wt(const float* __restrict__ W,
                                            unsigned short* __restrict__ WT,
                                            int K, int N){
  int i = blockIdx.x*256 + threadIdx.x;
  if (i >= K*N) return;
  int k = i % K, n = i / K;
  WT[i] = f2bf(W[(size_t)k*N + n]);
}

// ---- LN1 + transpose + bf16 x copy:
// x[b][p][c] f32 -> ht[b][c][p] bf16 (layernormed), xb[b][p][c] bf16 (raw copy)
__global__ __launch_bounds__(256) void k_ln1x(const float* __restrict__ x,
                                              const float* __restrict__ g,
                                              const float* __restrict__ be,
                                              unsigned short* __restrict__ ht,
                                              unsigned short* __restrict__ xb){
  __shared__ unsigned short tile[32][512];
  int blk = blockIdx.x;
  int b = blk >> 3, p0 = (blk & 7) << 5;
  int tid = threadIdx.x, w = tid >> 6, l = tid & 63;
  float4 gv0 = *(const float4*)(g  + l*8);
  float4 gv1 = *(const float4*)(g  + l*8 + 4);
  float4 bv0 = *(const float4*)(be + l*8);
  float4 bv1 = *(const float4*)(be + l*8 + 4);
  const float* xbase = x + (((size_t)b << 8) + p0) * 512;
  for (int i = 0; i < 8; ++i) {
    int pl = (i << 2) + w;
    const float* row = xbase + (size_t)pl*512 + l*8;
    float4 v0 = *(const float4*)row;
    float4 v1 = *(const float4*)(row + 4);
    u16x8 rc;
    rc[0]=f2bf(v0.x); rc[1]=f2bf(v0.y); rc[2]=f2bf(v0.z); rc[3]=f2bf(v0.w);
    rc[4]=f2bf(v1.x); rc[5]=f2bf(v1.y); rc[6]=f2bf(v1.z); rc[7]=f2bf(v1.w);
    *(u16x8*)(xb + (((size_t)b << 8) + p0 + pl)*512 + l*8) = rc;
    float s  = v0.x+v0.y+v0.z+v0.w + v1.x+v1.y+v1.z+v1.w;
    float s2 = v0.x*v0.x+v0.y*v0.y+v0.z*v0.z+v0.w*v0.w
             + v1.x*v1.x+v1.y*v1.y+v1.z*v1.z+v1.w*v1.w;
    #pragma unroll
    for (int off = 32; off; off >>= 1){ s += __shfl_xor(s, off); s2 += __shfl_xor(s2, off); }
    float mu = s * (1.0f/512.0f);
    float rs = rsqrtf(s2*(1.0f/512.0f) - mu*mu + 1e-6f);
    u16x8 o;
    o[0]=f2bf((v0.x-mu)*rs*gv0.x+bv0.x);
    o[1]=f2bf((v0.y-mu)*rs*gv0.y+bv0.y);
    o[2]=f2bf((v0.z-mu)*rs*gv0.z+bv0.z);
    o[3]=f2bf((v0.w-mu)*rs*gv0.w+bv0.w);
    o[4]=f2bf((v1.x-mu)*rs*gv1.x+bv1.x);
    o[5]=f2bf((v1.y-mu)*rs*gv1.y+bv1.y);
    o[6]=f2bf((v1.z-mu)*rs*gv1.z+bv1.z);
    o[7]=f2bf((v1.w-mu)*rs*gv1.w+bv1.w);
    *(u16x8*)(&tile[pl][l*8]) = o;
  }
  __syncthreads();
  unsigned short* hb = ht + ((size_t)b << 17);   // b * 512 * 256
  #pragma unroll
  for (int it = 0; it < 8; ++it) {
    int c = (it << 6) + (tid >> 2);
    int pch = (tid & 3) << 3;
    u16x8 o;
    #pragma unroll
    for (int j = 0; j < 8; ++j) o[j] = tile[pch + j][c];
    *(u16x8*)(hb + (size_t)c*256 + p0 + pch) = o;
  }
}

// ---- transpose-add + LN2:  h2[b][p][c] = LN( t[b][c][p] + xb[b][p][c] )
__global__ __launch_bounds__(256) void k_tl2(const unsigned short* __restrict__ t,
                                             const unsigned short* __restrict__ xb,
                                             const float* __restrict__ g,
                                             const float* __restrict__ be,
                                             unsigned short* __restrict__ h2){
  __shared__ unsigned short th[32][520];
  int blk = blockIdx.x;
  int b = blk >> 3, p0 = (blk & 7) << 5;
  int tid = threadIdx.x, w = tid >> 6, l = tid & 63;
  const unsigned short* tb = t + ((size_t)b << 17) + p0;
  #pragma unroll
  for (int it = 0; it < 8; ++it){
    int fc = (it << 8) + tid;
    int c = fc >> 2, pch = (fc & 3) << 3;
    u16x8 tv = *(const u16x8*)(tb + (size_t)c*256 + pch);
    #pragma unroll
    for (int j = 0; j < 8; ++j) th[pch + j][c] = tv[j];
  }
  __syncthreads();
  float4 gv0 = *(const float4*)(g  + l*8);
  float4 gv1 = *(const float4*)(g  + l*8 + 4);
  float4 bv0 = *(const float4*)(be + l*8);
  float4 bv1 = *(const float4*)(be + l*8 + 4);
  #pragma unroll
  for (int it = 0; it < 8; ++it){
    int pl = (it << 2) + w;
    u16x8 tvv = *(const u16x8*)(&th[pl][l*8]);
    size_t rowo = (((size_t)b << 8) + p0 + pl)*512 + l*8;
    u16x8 xvv = *(const u16x8*)(xb + rowo);
    float v[8];
    #pragma unroll
    for (int j = 0; j < 8; ++j) v[j] = bf2f(tvv[j]) + bf2f(xvv[j]);
    float s = 0.f, s2 = 0.f;
    #pragma unroll
    for (int j = 0; j < 8; ++j){ s += v[j]; s2 += v[j]*v[j]; }
    #pragma unroll
    for (int off = 32; off; off >>= 1){ s += __shfl_xor(s, off); s2 += __shfl_xor(s2, off); }
    float mu = s * (1.0f/512.0f);
    float rs = rsqrtf(s2*(1.0f/512.0f) - mu*mu + 1e-6f);
    u16x8 o;
    o[0]=f2bf((v[0]-mu)*rs*gv0.x+bv0.x);
    o[1]=f2bf((v[1]-mu)*rs*gv0.y+bv0.y);
    o[2]=f2bf((v[2]-mu)*rs*gv0.z+bv0.z);
    o[3]=f2bf((v[3]-mu)*rs*gv0.w+bv0.w);
    o[4]=f2bf((v[4]-mu)*rs*gv1.x+bv1.x);
    o[5]=f2bf((v[5]-mu)*rs*gv1.y+bv1.y);
    o[6]=f2bf((v[6]-mu)*rs*gv1.z+bv1.z);
    o[7]=f2bf((v[7]-mu)*rs*gv1.w+bv1.w);
    *(u16x8*)(h2 + rowo) = o;
  }
}

// ---- fused MLP: out = (gelu(A @ W1T^T + b1)) @ W2T^T + b2 [+ A if MODE==1]
// A: [M][K] bf16.  W1T: [NT][K], W2T: [NT][NT] bf16 ([n][k]).
// MT=32 rows/block, NT threads (NT/64 waves, each owning 64 output cols).
// Full A-tile staged once; weights read directly from global (L2-resident).
// 4 barriers total per block.
template<int MT, int K, int NT, int MODE>
__global__ __launch_bounds__(NT, 4) void k_mlp(
    const unsigned short* __restrict__ A,
    const unsigned short* __restrict__ W1T,
    const unsigned short* __restrict__ W2T,
    const float* __restrict__ b1v,
    const float* __restrict__ b2v,
    unsigned short* __restrict__ outb,
    float* __restrict__ outf)
{
  constexpr int CHA = K/8;     // 16B chunks per A row
  constexpr int CHU = NT/8;    // 16B chunks per U row
  constexpr int MI  = MT/16;   // m-frags per wave (wave covers all MT rows)
  __shared__ char lsA[MT*K*2];
  __shared__ char U[MT*NT*2];
  const int tid = threadIdx.x;
  const int wn = tid >> 6, l = tid & 63;
  const int la = l & 15, lg = l >> 4;
  const size_t m0 = (size_t)blockIdx.x * MT;
  const unsigned short* Ab = A + m0*K;

  // ---- stage full A tile (xor-8 chunk swizzle via inverse-swizzled source)
  #pragma unroll
  for (int i = 0; i < (MT*CHA)/NT; ++i){
    int q = i*NT + tid;
    int row = q / CHA, sc = q % CHA;
    int cc = sc ^ (row & 7);
    gl2lds16(Ab + (size_t)row*K + (cc << 3), lsA + q*16);
  }
  f32x4 acc[MI][4];
  #pragma unroll
  for (int i = 0; i < MI; ++i)
    #pragma unroll
    for (int j = 0; j < 4; ++j) acc[i][j] = (f32x4){0.f,0.f,0.f,0.f};
  __syncthreads();

  // ---- stage 1: acc = A @ W1, barrier-free loop (B from global/L2)
  #pragma unroll
  for (int ks = 0; ks < K/32; ++ks){
    int c = (ks << 2) + lg;
    bf16x8 af[MI], bfr[4];
    #pragma unroll
    for (int mi = 0; mi < MI; ++mi){
      int rr = (mi << 4) + la;
      af[mi] = *(const bf16x8*)(lsA + ((size_t)rr*CHA + (c ^ (rr & 7)))*16);
    }
    #pragma unroll
    for (int ni = 0; ni < 4; ++ni){
      int rn = (wn << 6) + (ni << 4) + la;
      bfr[ni] = *(const bf16x8*)(W1T + (size_t)rn*K + (c << 3));
    }
    #pragma unroll
    for (int mi = 0; mi < MI; ++mi)
      #pragma unroll
      for (int ni = 0; ni < 4; ++ni)
        acc[mi][ni] = __builtin_amdgcn_mfma_f32_16x16x32_bf16(af[mi], bfr[ni], acc[mi][ni], 0, 0, 0);
  }

  // ---- gelu epilogue -> U (bf16, chunk-swizzled), reset acc
  #pragma unroll
  for (int ni = 0; ni < 4; ++ni){
    int col = (wn << 6) + (ni << 4) + la;
    float bv = b1v[col];
    int ck = col >> 3, cw = col & 7;
    #pragma unroll
    for (int mi = 0; mi < MI; ++mi){
      int rb = (mi << 4) + (lg << 2);
      #pragma unroll
      for (int rg = 0; rg < 4; ++rg){
        float v = gelu_f(acc[mi][ni][rg] + bv);
        int r = rb + rg;
        *(unsigned short*)(U + ((size_t)r*NT + (((ck ^ (r & 7)) << 3) + cw))*2) = f2bf(v);
        acc[mi][ni][rg] = 0.0f;
      }
    }
  }
  __syncthreads();

  // ---- stage 2: acc = U @ W2, barrier-free loop
  #pragma unroll
  for (int ks = 0; ks < NT/32; ++ks){
    int c = (ks << 2) + lg;
    bf16x8 af[MI], bfr[4];
    #pragma unroll
    for (int mi = 0; mi < MI; ++mi){
      int rr = (mi << 4) + la;
      af[mi] = *(const bf16x8*)(U + ((size_t)rr*CHU + (c ^ (rr & 7)))*16);
    }
    #pragma unroll
    for (int ni = 0; ni < 4; ++ni){
      int rn = (wn << 6) + (ni << 4) + la;
      bfr[ni] = *(const bf16x8*)(W2T + (size_t)rn*NT + (c << 3));
    }
    #pragma unroll
    for (int mi = 0; mi < MI; ++mi)
      #pragma unroll
      for (int ni = 0; ni < 4; ++ni)
        acc[mi][ni] = __builtin_amdgcn_mfma_f32_16x16x32_bf16(af[mi], bfr[ni], acc[mi][ni], 0, 0, 0);
  }
  __syncthreads();   // everyone done reading U before overwrite

  // ---- final epilogue through U
  #pragma unroll
  for (int ni = 0; ni < 4; ++ni){
    int col = (wn << 6) + (ni << 4) + la;
    float bv = b2v[col];
    int ck = col >> 3, cw = col & 7;
    #pragma unroll
    for (int mi = 0; mi < MI; ++mi){
      int rb = (mi << 4) + (lg << 2);
      #pragma unroll
      for (int rg = 0; rg < 4; ++rg){
        float v = acc[mi][ni][rg] + bv;
        int r = rb + rg;
        *(unsigned short*)(U + ((size_t)r*NT + (((ck ^ (r & 7)) << 3) + cw))*2) = f2bf(v);
      }
    }
  }
  __syncthreads();

  // ---- coalesced global write (MODE 1: add residual from still-live lsA)
  #pragma unroll
  for (int i = 0; i < (MT*CHU)/NT; ++i){
    int q = i*NT + tid;
    int r = q / CHU, ck = q % CHU;
    u16x8 val = *(const u16x8*)(U + ((size_t)r*CHU + (ck ^ (r & 7)))*16);
    size_t go = (m0 + r)*NT + (ck << 3);
    if (MODE == 0){
      *(u16x8*)(outb + go) = val;
    } else {
      // K == NT for MODE 1 (channel mixer); residual from LDS A-tile
      u16x8 av = *(const u16x8*)(lsA + ((size_t)r*CHA + (ck ^ (r & 7)))*16);
      float4 o0, o1;
      o0.x = bf2f(val[0]) + bf2f(av[0]);
      o0.y = bf2f(val[1]) + bf2f(av[1]);
      o0.z = bf2f(val[2]) + bf2f(av[2]);
      o0.w = bf2f(val[3]) + bf2f(av[3]);
      o1.x = bf2f(val[4]) + bf2f(av[4]);
      o1.y = bf2f(val[5]) + bf2f(av[5]);
      o1.z = bf2f(val[6]) + bf2f(av[6]);
      o1.w = bf2f(val[7]) + bf2f(av[7]);
      *(float4*)(outf + go)     = o0;
      *(float4*)(outf + go + 4) = o1;
    }
  }
}

extern "C" void kernel_launch(void* const* d_in, const int* in_sizes, int n_in,
                              void* d_out, int out_size, void* d_ws, size_t ws_size,
                              hipStream_t stream) {
  const float* x   = (const float*)d_in[0];
  const float* lng = (const float*)d_in[1];
  const float* lnb = (const float*)d_in[2];
  const float* w1a = (const float*)d_in[3];
  const float* b1a = (const float*)d_in[4];
  const float* w1b = (const float*)d_in[5];
  const float* b1b = (const float*)d_in[6];
  const float* w2a = (const float*)d_in[7];
  const float* b2a = (const float*)d_in[8];
  const float* w2b = (const float*)d_in[9];
  const float* b2b = (const float*)d_in[10];
  float* out = (float*)d_out;
  char* ws = (char*)d_ws;
  unsigned short* bufA = (unsigned short*)ws;                         // 64 MiB
  unsigned short* bufB = (unsigned short*)(ws + (size_t)(64u << 20)); // 64 MiB
  unsigned short* wt1a = (unsigned short*)(ws + (size_t)(128u << 20));
  unsigned short* wt1b = wt1a + 256*256;
  unsigned short* wt2a = wt1b + 256*256;
  unsigned short* wt2b = wt2a + 512*512;
  unsigned short* xb   = (unsigned short*)d_out;  // scratch in d_out (consumed
                                                  // by k_tl2 before final write)

  k_wt<<<256,  256, 0, stream>>>(w1a, wt1a, 256, 256);
  k_wt<<<256,  256, 0, stream>>>(w1b, wt1b, 256, 256);
  k_wt<<<1024, 256, 0, stream>>>(w2a, wt2a, 512, 512);
  k_wt<<<1024, 256, 0, stream>>>(w2b, wt2b, 512, 512);

  // token mixing: ht = LN1(x)^T ; t = gelu(ht@w1a+b1a)@w1b+b1b
  k_ln1x<<<2048, 256, 0, stream>>>(x, lng, lnb, bufA, xb);
  k_mlp<32, 256, 256, 0><<<4096, 256, 0, stream>>>(bufA, wt1a, wt1b, b1a, b1b, bufB, nullptr);

  // residual + LN2 (x2 never materialized in f32)
  k_tl2<<<2048, 256, 0, stream>>>(bufB, xb, lng, lnb, bufA);

  // channel mixing: out = h2 + gelu(h2@w2a+b2a)@w2b+b2b
  k_mlp<32, 512, 512, 1><<<2048, 512, 0, stream>>>(bufA, wt2a, wt2b, b2a, b2b, nullptr, out);
}

// Round 4
// 293.201 us; speedup vs baseline: 1.7219x; 1.7219x over previous
//
#include <hip/hip_runtime.h>
#include <hip/hip_bf16.h>
#include <math.h>

typedef __bf16 bf16x8 __attribute__((ext_vector_type(8)));
typedef float f32x4 __attribute__((ext_vector_type(4)));
typedef unsigned short u16x8 __attribute__((ext_vector_type(8)));

#define DEV __device__ __forceinline__

DEV unsigned short f2bf(float f){ __hip_bfloat16 h=__float2bfloat16(f); unsigned short u; __builtin_memcpy(&u,&h,2); return u; }
DEV float bf2f(unsigned short u){ __hip_bfloat16 h; __builtin_memcpy(&h,&u,2); return __bfloat162float(h); }

// tanh-form GELU: exp is HW (v_exp_f32), rcp is HW.
DEV float gelu_f(float v){
  float u = v*(0.7978845608f + 0.0356774081f*v*v);
  float e = __expf(2.0f*u);
  float t = 1.0f - 2.0f*__builtin_amdgcn_rcpf(e + 1.0f);
  return 0.5f*v*(1.0f + t);
}

DEV void gl2lds16(const void* g, void* l){
  __builtin_amdgcn_global_load_lds((const __attribute__((address_space(1))) void*)g,
                                   (__attribute__((address_space(3))) void*)l, 16, 0, 0);
}

// ---- weight transpose: WT[n][k] (bf16) = W[k][n] (f32)
__global__ __launch_bounds__(256) void k_wt(const float* __restrict__ W,
                                            unsigned short* __restrict__ WT,
                                            int K, int N){
  int i = blockIdx.x*256 + threadIdx.x;
  if (i >= K*N) return;
  int k = i % K, n = i / K;
  WT[i] = f2bf(W[(size_t)k*N + n]);
}

// ---- LN1 + transpose + bf16 x copy:
// x[b][p][c] f32 -> ht[b][c][p] bf16 (layernormed), xb[b][p][c] bf16 (raw copy)
__global__ __launch_bounds__(256) void k_ln1x(const float* __restrict__ x,
                                              const float* __restrict__ g,
                                              const float* __restrict__ be,
                                              unsigned short* __restrict__ ht,
                                              unsigned short* __restrict__ xb){
  __shared__ unsigned short tile[32][512];
  int blk = blockIdx.x;
  int b = blk >> 3, p0 = (blk & 7) << 5;
  int tid = threadIdx.x, w = tid >> 6, l = tid & 63;
  float4 gv0 = *(const float4*)(g  + l*8);
  float4 gv1 = *(const float4*)(g  + l*8 + 4);
  float4 bv0 = *(const float4*)(be + l*8);
  float4 bv1 = *(const float4*)(be + l*8 + 4);
  const float* xbase = x + (((size_t)b << 8) + p0) * 512;
  for (int i = 0; i < 8; ++i) {
    int pl = (i << 2) + w;
    const float* row = xbase + (size_t)pl*512 + l*8;
    float4 v0 = *(const float4*)row;
    float4 v1 = *(const float4*)(row + 4);
    u16x8 rc;
    rc[0]=f2bf(v0.x); rc[1]=f2bf(v0.y); rc[2]=f2bf(v0.z); rc[3]=f2bf(v0.w);
    rc[4]=f2bf(v1.x); rc[5]=f2bf(v1.y); rc[6]=f2bf(v1.z); rc[7]=f2bf(v1.w);
    *(u16x8*)(xb + (((size_t)b << 8) + p0 + pl)*512 + l*8) = rc;
    float s  = v0.x+v0.y+v0.z+v0.w + v1.x+v1.y+v1.z+v1.w;
    float s2 = v0.x*v0.x+v0.y*v0.y+v0.z*v0.z+v0.w*v0.w
             + v1.x*v1.x+v1.y*v1.y+v1.z*v1.z+v1.w*v1.w;
    #pragma unroll
    for (int off = 32; off; off >>= 1){ s += __shfl_xor(s, off); s2 += __shfl_xor(s2, off); }
    float mu = s * (1.0f/512.0f);
    float rs = rsqrtf(s2*(1.0f/512.0f) - mu*mu + 1e-6f);
    u16x8 o;
    o[0]=f2bf((v0.x-mu)*rs*gv0.x+bv0.x);
    o[1]=f2bf((v0.y-mu)*rs*gv0.y+bv0.y);
    o[2]=f2bf((v0.z-mu)*rs*gv0.z+bv0.z);
    o[3]=f2bf((v0.w-mu)*rs*gv0.w+bv0.w);
    o[4]=f2bf((v1.x-mu)*rs*gv1.x+bv1.x);
    o[5]=f2bf((v1.y-mu)*rs*gv1.y+bv1.y);
    o[6]=f2bf((v1.z-mu)*rs*gv1.z+bv1.z);
    o[7]=f2bf((v1.w-mu)*rs*gv1.w+bv1.w);
    *(u16x8*)(&tile[pl][l*8]) = o;
  }
  __syncthreads();
  unsigned short* hb = ht + ((size_t)b << 17);   // b * 512 * 256
  #pragma unroll
  for (int it = 0; it < 8; ++it) {
    int c = (it << 6) + (tid >> 2);
    int pch = (tid & 3) << 3;
    u16x8 o;
    #pragma unroll
    for (int j = 0; j < 8; ++j) o[j] = tile[pch + j][c];
    *(u16x8*)(hb + (size_t)c*256 + p0 + pch) = o;
  }
}

// ---- transpose-add + LN2:  h2[b][p][c] = LN( t[b][c][p] + xb[b][p][c] )
__global__ __launch_bounds__(256) void k_tl2(const unsigned short* __restrict__ t,
                                             const unsigned short* __restrict__ xb,
                                             const float* __restrict__ g,
                                             const float* __restrict__ be,
                                             unsigned short* __restrict__ h2){
  __shared__ unsigned short th[32][520];
  int blk = blockIdx.x;
  int b = blk >> 3, p0 = (blk & 7) << 5;
  int tid = threadIdx.x, w = tid >> 6, l = tid & 63;
  const unsigned short* tb = t + ((size_t)b << 17) + p0;
  #pragma unroll
  for (int it = 0; it < 8; ++it){
    int fc = (it << 8) + tid;
    int c = fc >> 2, pch = (fc & 3) << 3;
    u16x8 tv = *(const u16x8*)(tb + (size_t)c*256 + pch);
    #pragma unroll
    for (int j = 0; j < 8; ++j) th[pch + j][c] = tv[j];
  }
  __syncthreads();
  float4 gv0 = *(const float4*)(g  + l*8);
  float4 gv1 = *(const float4*)(g  + l*8 + 4);
  float4 bv0 = *(const float4*)(be + l*8);
  float4 bv1 = *(const float4*)(be + l*8 + 4);
  #pragma unroll
  for (int it = 0; it < 8; ++it){
    int pl = (it << 2) + w;
    u16x8 tvv = *(const u16x8*)(&th[pl][l*8]);
    size_t rowo = (((size_t)b << 8) + p0 + pl)*512 + l*8;
    u16x8 xvv = *(const u16x8*)(xb + rowo);
    float v[8];
    #pragma unroll
    for (int j = 0; j < 8; ++j) v[j] = bf2f(tvv[j]) + bf2f(xvv[j]);
    float s = 0.f, s2 = 0.f;
    #pragma unroll
    for (int j = 0; j < 8; ++j){ s += v[j]; s2 += v[j]*v[j]; }
    #pragma unroll
    for (int off = 32; off; off >>= 1){ s += __shfl_xor(s, off); s2 += __shfl_xor(s2, off); }
    float mu = s * (1.0f/512.0f);
    float rs = rsqrtf(s2*(1.0f/512.0f) - mu*mu + 1e-6f);
    u16x8 o;
    o[0]=f2bf((v[0]-mu)*rs*gv0.x+bv0.x);
    o[1]=f2bf((v[1]-mu)*rs*gv0.y+bv0.y);
    o[2]=f2bf((v[2]-mu)*rs*gv0.z+bv0.z);
    o[3]=f2bf((v[3]-mu)*rs*gv0.w+bv0.w);
    o[4]=f2bf((v[4]-mu)*rs*gv1.x+bv1.x);
    o[5]=f2bf((v[5]-mu)*rs*gv1.y+bv1.y);
    o[6]=f2bf((v[6]-mu)*rs*gv1.z+bv1.z);
    o[7]=f2bf((v[7]-mu)*rs*gv1.w+bv1.w);
    *(u16x8*)(h2 + rowo) = o;
  }
}

// ---- m97-style 128x128 GEMM, C[m][n] = epi(sum_k A[m][k]*BT[n][k] + bias[n])
// A: [M][K] bf16 row-major; BT: [N][K] bf16 row-major; K = KT*64.
// MODE 0: outb = bf16(gelu(v))   MODE 1: outb = bf16(v)
// MODE 2: outf = f32(v) + f32(res[m][n])
// 256 threads = 4 waves (2m x 2n), each wave 64x64 output.
// Plain 2-barrier k-loop (inter-block overlap at 3 blocks/CU), LDS-staged
// coalesced epilogue (pitch 176 B -> conflict-light, 16B-aligned reads).
template<int N, int KT, int MODE>
__global__ __launch_bounds__(256, 2) void k_gemm(
    const unsigned short* __restrict__ A,
    const unsigned short* __restrict__ BT,
    const float* __restrict__ bias,
    unsigned short* __restrict__ outb,
    float* __restrict__ outf,
    const unsigned short* __restrict__ res)
{
  constexpr int K = KT*64;
  constexpr int nTn = N/128;
  constexpr int EPITCH = 176;            // bytes per row in epilogue tile (88 cols)
  constexpr int EREG   = 64*EPITCH;      // 11264 B per wave region
  __shared__ char lds[4*EREG];           // 45056 B; k-loop uses first 32768
  char* lsA = lds;
  char* lsB = lds + 16384;

  // XCD-chunked bijective swizzle (grid divisible by 8 here)
  int nwg = gridDim.x, bid = blockIdx.x;
  int wgid = ((nwg & 7) == 0) ? ((bid & 7)*(nwg >> 3) + (bid >> 3)) : bid;
  int tm = wgid / nTn, tn = wgid % nTn;
  size_t m0 = (size_t)tm * 128;
  int n0 = tn * 128;

  const int tid = threadIdx.x;
  const int w = tid >> 6, l = tid & 63;
  const int wm = w >> 1, wn = w & 1;
  const int la = l & 15, lg = l >> 4;

  f32x4 acc[4][4];
  #pragma unroll
  for (int i = 0; i < 4; ++i)
    #pragma unroll
    for (int j = 0; j < 4; ++j) acc[i][j] = (f32x4){0.f,0.f,0.f,0.f};

  for (int kt = 0; kt < KT; ++kt){
    int kb = kt << 6;
    #pragma unroll
    for (int i = 0; i < 4; ++i){
      int q = (i << 8) + tid;
      int row = q >> 3, sc = q & 7;
      int cc = sc ^ (row & 7);
      gl2lds16(A  + (m0 + row)*K + kb + (cc << 3), lsA + q*16);
      gl2lds16(BT + (size_t)(n0 + row)*K + kb + (cc << 3), lsB + q*16);
    }
    __syncthreads();
    #pragma unroll
    for (int ks = 0; ks < 2; ++ks){
      int c = (ks << 2) + lg;
      bf16x8 af[4], bfr[4];
      #pragma unroll
      for (int mi = 0; mi < 4; ++mi){
        int rr = (wm << 6) + (mi << 4) + la;
        af[mi] = *(const bf16x8*)(lsA + ((rr << 3) + (c ^ (rr & 7)))*16);
      }
      #pragma unroll
      for (int ni = 0; ni < 4; ++ni){
        int rn = (wn << 6) + (ni << 4) + la;
        bfr[ni] = *(const bf16x8*)(lsB + ((rn << 3) + (c ^ (rn & 7)))*16);
      }
      #pragma unroll
      for (int mi = 0; mi < 4; ++mi)
        #pragma unroll
        for (int ni = 0; ni < 4; ++ni)
          acc[mi][ni] = __builtin_amdgcn_mfma_f32_16x16x32_bf16(af[mi], bfr[ni], acc[mi][ni], 0, 0, 0);
    }
    __syncthreads();
  }

  // ---- epilogue: bias (+gelu) -> per-wave LDS tile (pitch 176 B)
  char* ep = lds + w*EREG;
  #pragma unroll
  for (int ni = 0; ni < 4; ++ni){
    int colw = (ni << 4) + la;                       // col within wave tile
    float bv = bias[n0 + (wn << 6) + colw];
    #pragma unroll
    for (int mi = 0; mi < 4; ++mi){
      #pragma unroll
      for (int rg = 0; rg < 4; ++rg){
        float v = acc[mi][ni][rg] + bv;
        if (MODE == 0) v = gelu_f(v);
        int r = (mi << 4) + (lg << 2) + rg;
        *(unsigned short*)(ep + r*EPITCH + colw*2) = f2bf(v);
      }
    }
  }
  __syncthreads();

  // ---- coalesced global write: each thread 8 chunks of 8 cols
  #pragma unroll
  for (int i = 0; i < 8; ++i){
    int q = (i << 8) + tid;
    int r = q >> 4, ck = q & 15;
    int wreg = ((r >> 6) << 1) | (ck >> 3);
    u16x8 val = *(const u16x8*)(lds + wreg*EREG + (r & 63)*EPITCH + (ck & 7)*16);
    size_t go = (m0 + r)*N + n0 + (ck << 3);
    if (MODE != 2){
      *(u16x8*)(outb + go) = val;
    } else {
      u16x8 rv = *(const u16x8*)(res + go);
      float4 o0, o1;
      o0.x = bf2f(val[0]) + bf2f(rv[0]);
      o0.y = bf2f(val[1]) + bf2f(rv[1]);
      o0.z = bf2f(val[2]) + bf2f(rv[2]);
      o0.w = bf2f(val[3]) + bf2f(rv[3]);
      o1.x = bf2f(val[4]) + bf2f(rv[4]);
      o1.y = bf2f(val[5]) + bf2f(rv[5]);
      o1.z = bf2f(val[6]) + bf2f(rv[6]);
      o1.w = bf2f(val[7]) + bf2f(rv[7]);
      *(float4*)(outf + go)     = o0;
      *(float4*)(outf + go + 4) = o1;
    }
  }
}

extern "C" void kernel_launch(void* const* d_in, const int* in_sizes, int n_in,
                              void* d_out, int out_size, void* d_ws, size_t ws_size,
                              hipStream_t stream) {
  const float* x   = (const float*)d_in[0];
  const float* lng = (const float*)d_in[1];
  const float* lnb = (const float*)d_in[2];
  const float* w1a = (const float*)d_in[3];
  const float* b1a = (const float*)d_in[4];
  const float* w1b = (const float*)d_in[5];
  const float* b1b = (const float*)d_in[6];
  const float* w2a = (const float*)d_in[7];
  const float* b2a = (const float*)d_in[8];
  const float* w2b = (const float*)d_in[9];
  const float* b2b = (const float*)d_in[10];
  float* out = (float*)d_out;
  char* ws = (char*)d_ws;
  unsigned short* bufA = (unsigned short*)ws;                         // 64 MiB
  unsigned short* bufB = (unsigned short*)(ws + (size_t)(64u << 20)); // 64 MiB
  unsigned short* wt1a = (unsigned short*)(ws + (size_t)(128u << 20));
  unsigned short* wt1b = wt1a + 256*256;
  unsigned short* wt2a = wt1b + 256*256;
  unsigned short* wt2b = wt2a + 512*512;
  unsigned short* xb   = (unsigned short*)d_out;  // scratch in d_out (consumed
                                                  // by k_tl2 before final write)

  k_wt<<<256,  256, 0, stream>>>(w1a, wt1a, 256, 256);
  k_wt<<<256,  256, 0, stream>>>(w1b, wt1b, 256, 256);
  k_wt<<<1024, 256, 0, stream>>>(w2a, wt2a, 512, 512);
  k_wt<<<1024, 256, 0, stream>>>(w2b, wt2b, 512, 512);

  // token mixing over [B*C=131072][P=256]: ht -> gelu GEMM -> GEMM -> t
  k_ln1x<<<2048, 256, 0, stream>>>(x, lng, lnb, bufA, xb);
  k_gemm<256, 4, 0><<<2048, 256, 0, stream>>>(bufA, wt1a, b1a, bufB, nullptr, nullptr);
  k_gemm<256, 4, 1><<<2048, 256, 0, stream>>>(bufB, wt1b, b1b, bufA, nullptr, nullptr);

  // residual + LN2 (x2 never materialized in f32): h2 in bufB
  k_tl2<<<2048, 256, 0, stream>>>(bufA, xb, lng, lnb, bufB);

  // channel mixing over [B*P=65536][C=512]: gelu GEMM -> GEMM (+h2 residual, f32 out)
  k_gemm<512, 8, 0><<<2048, 256, 0, stream>>>(bufB, wt2a, b2a, bufA, nullptr, nullptr);
  k_gemm<512, 8, 2><<<2048, 256, 0, stream>>>(bufA, wt2b, b2b, nullptr, out, bufB);
}

// Round 5
// 280.710 us; speedup vs baseline: 1.7986x; 1.0445x over previous
//
#include <hip/hip_runtime.h>
#include <hip/hip_bf16.h>
#include <math.h>

typedef __bf16 bf16x8 __attribute__((ext_vector_type(8)));
typedef float f32x4 __attribute__((ext_vector_type(4)));
typedef unsigned short u16x8 __attribute__((ext_vector_type(8)));

#define DEV __device__ __forceinline__

DEV unsigned short f2bf(float f){ __hip_bfloat16 h=__float2bfloat16(f); unsigned short u; __builtin_memcpy(&u,&h,2); return u; }
DEV float bf2f(unsigned short u){ __hip_bfloat16 h; __builtin_memcpy(&h,&u,2); return __bfloat162float(h); }

// tanh-form GELU: exp is HW (v_exp_f32), rcp is HW.
DEV float gelu_f(float v){
  float u = v*(0.7978845608f + 0.0356774081f*v*v);
  float e = __expf(2.0f*u);
  float t = 1.0f - 2.0f*__builtin_amdgcn_rcpf(e + 1.0f);
  return 0.5f*v*(1.0f + t);
}

DEV void gl2lds16(const void* g, void* l){
  __builtin_amdgcn_global_load_lds((const __attribute__((address_space(1))) void*)g,
                                   (__attribute__((address_space(3))) void*)l, 16, 0, 0);
}

// ---- all four weight transposes in one launch: WT[n][k] (bf16) = W[k][n] (f32)
__global__ __launch_bounds__(256) void k_wt4(const float* __restrict__ w1a,
                                             const float* __restrict__ w1b,
                                             const float* __restrict__ w2a,
                                             const float* __restrict__ w2b,
                                             unsigned short* __restrict__ o1a,
                                             unsigned short* __restrict__ o1b,
                                             unsigned short* __restrict__ o2a,
                                             unsigned short* __restrict__ o2b){
  int i = blockIdx.x*256 + threadIdx.x;
  const float* W; unsigned short* O; int KN, j;
  if (i < 131072){
    if (i < 65536){ W = w1a; O = o1a; j = i; }
    else          { W = w1b; O = o1b; j = i - 65536; }
    KN = 256;
  } else {
    int i2 = i - 131072;
    if (i2 < 262144){ W = w2a; O = o2a; j = i2; }
    else            { W = w2b; O = o2b; j = i2 - 262144; }
    KN = 512;
  }
  int k = j % KN, n = j / KN;
  O[j] = f2bf(W[(size_t)k*KN + n]);
}

// ---- LN1 + transpose + bf16 x copy:
// x[b][p][c] f32 -> ht[b][c][p] bf16 (layernormed), xb[b][p][c] bf16 (raw copy)
// XOR-swizzled LDS tile: (p,c) stored at col c ^ ((p>>3)<<4) -> b128 writes
// stay aligned+conflict-free, scalar transpose reads hit all 32 banks.
__global__ __launch_bounds__(256) void k_ln1x(const float* __restrict__ x,
                                              const float* __restrict__ g,
                                              const float* __restrict__ be,
                                              unsigned short* __restrict__ ht,
                                              unsigned short* __restrict__ xb){
  __shared__ unsigned short tile[32][512];
  int blk = blockIdx.x;
  int b = blk >> 3, p0 = (blk & 7) << 5;
  int tid = threadIdx.x, w = tid >> 6, l = tid & 63;
  float4 gv0 = *(const float4*)(g  + l*8);
  float4 gv1 = *(const float4*)(g  + l*8 + 4);
  float4 bv0 = *(const float4*)(be + l*8);
  float4 bv1 = *(const float4*)(be + l*8 + 4);
  const float* xbase = x + (((size_t)b << 8) + p0) * 512;
  #pragma unroll
  for (int i = 0; i < 8; ++i) {
    int pl = (i << 2) + w;
    const float* row = xbase + (size_t)pl*512 + l*8;
    float4 v0 = *(const float4*)row;
    float4 v1 = *(const float4*)(row + 4);
    u16x8 rc;
    rc[0]=f2bf(v0.x); rc[1]=f2bf(v0.y); rc[2]=f2bf(v0.z); rc[3]=f2bf(v0.w);
    rc[4]=f2bf(v1.x); rc[5]=f2bf(v1.y); rc[6]=f2bf(v1.z); rc[7]=f2bf(v1.w);
    *(u16x8*)(xb + (((size_t)b << 8) + p0 + pl)*512 + l*8) = rc;
    float s  = v0.x+v0.y+v0.z+v0.w + v1.x+v1.y+v1.z+v1.w;
    float s2 = v0.x*v0.x+v0.y*v0.y+v0.z*v0.z+v0.w*v0.w
             + v1.x*v1.x+v1.y*v1.y+v1.z*v1.z+v1.w*v1.w;
    #pragma unroll
    for (int off = 32; off; off >>= 1){ s += __shfl_xor(s, off); s2 += __shfl_xor(s2, off); }
    float mu = s * (1.0f/512.0f);
    float rs = rsqrtf(s2*(1.0f/512.0f) - mu*mu + 1e-6f);
    u16x8 o;
    o[0]=f2bf((v0.x-mu)*rs*gv0.x+bv0.x);
    o[1]=f2bf((v0.y-mu)*rs*gv0.y+bv0.y);
    o[2]=f2bf((v0.z-mu)*rs*gv0.z+bv0.z);
    o[3]=f2bf((v0.w-mu)*rs*gv0.w+bv0.w);
    o[4]=f2bf((v1.x-mu)*rs*gv1.x+bv1.x);
    o[5]=f2bf((v1.y-mu)*rs*gv1.y+bv1.y);
    o[6]=f2bf((v1.z-mu)*rs*gv1.z+bv1.z);
    o[7]=f2bf((v1.w-mu)*rs*gv1.w+bv1.w);
    *(u16x8*)(&tile[pl][(l ^ ((pl >> 3) << 1)) << 3]) = o;   // swizzled chunk
  }
  __syncthreads();
  unsigned short* hb = ht + ((size_t)b << 17);   // b * 512 * 256
  #pragma unroll
  for (int it = 0; it < 8; ++it) {
    int c = (it << 6) + (tid >> 2);
    int q = tid & 3, pch = q << 3;
    int cs = c ^ (q << 4);                       // swizzled source column
    u16x8 o;
    #pragma unroll
    for (int j = 0; j < 8; ++j) o[j] = tile[pch + j][cs];
    *(u16x8*)(hb + (size_t)c*256 + p0 + pch) = o;
  }
}

// ---- streaming residual + LN2 (t already in [b][p][c] layout):
// h2[r][c] = LN( t[r][c] + xb[r][c] ),  r = (b,p)
__global__ __launch_bounds__(256) void k_tl2s(const unsigned short* __restrict__ t,
                                              const unsigned short* __restrict__ xb,
                                              const float* __restrict__ g,
                                              const float* __restrict__ be,
                                              unsigned short* __restrict__ h2){
  int tid = threadIdx.x, w = tid >> 6, l = tid & 63;
  float4 gv0 = *(const float4*)(g  + l*8);
  float4 gv1 = *(const float4*)(g  + l*8 + 4);
  float4 bv0 = *(const float4*)(be + l*8);
  float4 bv1 = *(const float4*)(be + l*8 + 4);
  int wid = blockIdx.x*4 + w;
  for (int r = wid; r < 65536; r += gridDim.x*4){
    size_t off = (size_t)r*512 + l*8;
    u16x8 tv = *(const u16x8*)(t + off);
    u16x8 xv = *(const u16x8*)(xb + off);
    float v[8];
    #pragma unroll
    for (int j = 0; j < 8; ++j) v[j] = bf2f(tv[j]) + bf2f(xv[j]);
    float s = 0.f, s2 = 0.f;
    #pragma unroll
    for (int j = 0; j < 8; ++j){ s += v[j]; s2 += v[j]*v[j]; }
    #pragma unroll
    for (int off2 = 32; off2; off2 >>= 1){ s += __shfl_xor(s, off2); s2 += __shfl_xor(s2, off2); }
    float mu = s * (1.0f/512.0f);
    float rs = rsqrtf(s2*(1.0f/512.0f) - mu*mu + 1e-6f);
    u16x8 o;
    o[0]=f2bf((v[0]-mu)*rs*gv0.x+bv0.x);
    o[1]=f2bf((v[1]-mu)*rs*gv0.y+bv0.y);
    o[2]=f2bf((v[2]-mu)*rs*gv0.z+bv0.z);
    o[3]=f2bf((v[3]-mu)*rs*gv0.w+bv0.w);
    o[4]=f2bf((v[4]-mu)*rs*gv1.x+bv1.x);
    o[5]=f2bf((v[5]-mu)*rs*gv1.y+bv1.y);
    o[6]=f2bf((v[6]-mu)*rs*gv1.z+bv1.z);
    o[7]=f2bf((v[7]-mu)*rs*gv1.w+bv1.w);
    *(u16x8*)(h2 + off) = o;
  }
}

// ---- m97-style 128x128 GEMM, C[m][n] = epi(sum_k A[m][k]*BT[n][k] + bias[n])
// MODE 0: outb = bf16(gelu(v))   MODE 1: outb = bf16(v)
// MODE 2: outf = f32(v) + f32(res[m][n])
template<int N, int KT, int MODE>
__global__ __launch_bounds__(256, 2) void k_gemm(
    const unsigned short* __restrict__ A,
    const unsigned short* __restrict__ BT,
    const float* __restrict__ bias,
    unsigned short* __restrict__ outb,
    float* __restrict__ outf,
    const unsigned short* __restrict__ res)
{
  constexpr int K = KT*64;
  constexpr int nTn = N/128;
  constexpr int EPITCH = 176;
  constexpr int EREG   = 64*EPITCH;
  __shared__ char lds[4*EREG];
  char* lsA = lds;
  char* lsB = lds + 16384;

  int nwg = gridDim.x, bid = blockIdx.x;
  int wgid = ((nwg & 7) == 0) ? ((bid & 7)*(nwg >> 3) + (bid >> 3)) : bid;
  int tm = wgid / nTn, tn = wgid % nTn;
  size_t m0 = (size_t)tm * 128;
  int n0 = tn * 128;

  const int tid = threadIdx.x;
  const int w = tid >> 6, l = tid & 63;
  const int wm = w >> 1, wn = w & 1;
  const int la = l & 15, lg = l >> 4;

  f32x4 acc[4][4];
  #pragma unroll
  for (int i = 0; i < 4; ++i)
    #pragma unroll
    for (int j = 0; j < 4; ++j) acc[i][j] = (f32x4){0.f,0.f,0.f,0.f};

  for (int kt = 0; kt < KT; ++kt){
    int kb = kt << 6;
    #pragma unroll
    for (int i = 0; i < 4; ++i){
      int q = (i << 8) + tid;
      int row = q >> 3, sc = q & 7;
      int cc = sc ^ (row & 7);
      gl2lds16(A  + (m0 + row)*K + kb + (cc << 3), lsA + q*16);
      gl2lds16(BT + (size_t)(n0 + row)*K + kb + (cc << 3), lsB + q*16);
    }
    __syncthreads();
    #pragma unroll
    for (int ks = 0; ks < 2; ++ks){
      int c = (ks << 2) + lg;
      bf16x8 af[4], bfr[4];
      #pragma unroll
      for (int mi = 0; mi < 4; ++mi){
        int rr = (wm << 6) + (mi << 4) + la;
        af[mi] = *(const bf16x8*)(lsA + ((rr << 3) + (c ^ (rr & 7)))*16);
      }
      #pragma unroll
      for (int ni = 0; ni < 4; ++ni){
        int rn = (wn << 6) + (ni << 4) + la;
        bfr[ni] = *(const bf16x8*)(lsB + ((rn << 3) + (c ^ (rn & 7)))*16);
      }
      #pragma unroll
      for (int mi = 0; mi < 4; ++mi)
        #pragma unroll
        for (int ni = 0; ni < 4; ++ni)
          acc[mi][ni] = __builtin_amdgcn_mfma_f32_16x16x32_bf16(af[mi], bfr[ni], acc[mi][ni], 0, 0, 0);
    }
    __syncthreads();
  }

  char* ep = lds + w*EREG;
  #pragma unroll
  for (int ni = 0; ni < 4; ++ni){
    int colw = (ni << 4) + la;
    float bv = bias[n0 + (wn << 6) + colw];
    #pragma unroll
    for (int mi = 0; mi < 4; ++mi){
      #pragma unroll
      for (int rg = 0; rg < 4; ++rg){
        float v = acc[mi][ni][rg] + bv;
        if (MODE == 0) v = gelu_f(v);
        int r = (mi << 4) + (lg << 2) + rg;
        *(unsigned short*)(ep + r*EPITCH + colw*2) = f2bf(v);
      }
    }
  }
  __syncthreads();

  #pragma unroll
  for (int i = 0; i < 8; ++i){
    int q = (i << 8) + tid;
    int r = q >> 4, ck = q & 15;
    int wreg = ((r >> 6) << 1) | (ck >> 3);
    u16x8 val = *(const u16x8*)(lds + wreg*EREG + (r & 63)*EPITCH + (ck & 7)*16);
    size_t go = (m0 + r)*N + n0 + (ck << 3);
    if (MODE != 2){
      *(u16x8*)(outb + go) = val;
    } else {
      u16x8 rv = *(const u16x8*)(res + go);
      float4 o0, o1;
      o0.x = bf2f(val[0]) + bf2f(rv[0]);
      o0.y = bf2f(val[1]) + bf2f(rv[1]);
      o0.z = bf2f(val[2]) + bf2f(rv[2]);
      o0.w = bf2f(val[3]) + bf2f(rv[3]);
      o1.x = bf2f(val[4]) + bf2f(rv[4]);
      o1.y = bf2f(val[5]) + bf2f(rv[5]);
      o1.z = bf2f(val[6]) + bf2f(rv[6]);
      o1.w = bf2f(val[7]) + bf2f(rv[7]);
      *(float4*)(outf + go)     = o0;
      *(float4*)(outf + go + 4) = o1;
    }
  }
}

// ---- token G2, transposed-output: t_nat[b][p][c] = sum_k wt1b[p][k]*U[(b,c)][k] + b1b[p]
// A = wt1b [256][256] (L2-resident, shared by all blocks), BT = U [(b,c)][256].
// Same 128^2 structure; bias is per-ROW; output written in [b][p][c] layout.
__global__ __launch_bounds__(256, 2) void k_gemmT(
    const unsigned short* __restrict__ A,
    const unsigned short* __restrict__ BT,
    const float* __restrict__ bias,
    unsigned short* __restrict__ outb)
{
  constexpr int K = 256, KT = 4;
  constexpr int EPITCH = 176;
  constexpr int EREG   = 64*EPITCH;
  __shared__ char lds[4*EREG];
  char* lsA = lds;
  char* lsB = lds + 16384;

  int nwg = gridDim.x, bid = blockIdx.x;
  int wgid = (bid & 7)*(nwg >> 3) + (bid >> 3);   // grid is 2048, divisible by 8
  int tm = wgid & 1, tn = wgid >> 1;              // paired m-tiles share B-panel
  size_t m0 = (size_t)tm * 128;
  int n0 = tn * 128;
  int bb = n0 >> 9, c0 = n0 & 511;

  const int tid = threadIdx.x;
  const int w = tid >> 6, l = tid & 63;
  const int wm = w >> 1, wn = w & 1;
  const int la = l & 15, lg = l >> 4;

  f32x4 acc[4][4];
  #pragma unroll
  for (int i = 0; i < 4; ++i)
    #pragma unroll
    for (int j = 0; j < 4; ++j) acc[i][j] = (f32x4){0.f,0.f,0.f,0.f};

  for (int kt = 0; kt < KT; ++kt){
    int kb = kt << 6;
    #pragma unroll
    for (int i = 0; i < 4; ++i){
      int q = (i << 8) + tid;
      int row = q >> 3, sc = q & 7;
      int cc = sc ^ (row & 7);
      gl2lds16(A  + (m0 + row)*K + kb + (cc << 3), lsA + q*16);
      gl2lds16(BT + (size_t)(n0 + row)*K + kb + (cc << 3), lsB + q*16);
    }
    __syncthreads();
    #pragma unroll
    for (int ks = 0; ks < 2; ++ks){
      int c = (ks << 2) + lg;
      bf16x8 af[4], bfr[4];
      #pragma unroll
      for (int mi = 0; mi < 4; ++mi){
        int rr = (wm << 6) + (mi << 4) + la;
        af[mi] = *(const bf16x8*)(lsA + ((rr << 3) + (c ^ (rr & 7)))*16);
      }
      #pragma unroll
      for (int ni = 0; ni < 4; ++ni){
        int rn = (wn << 6) + (ni << 4) + la;
        bfr[ni] = *(const bf16x8*)(lsB + ((rn << 3) + (c ^ (rn & 7)))*16);
      }
      #pragma unroll
      for (int mi = 0; mi < 4; ++mi)
        #pragma unroll
        for (int ni = 0; ni < 4; ++ni)
          acc[mi][ni] = __builtin_amdgcn_mfma_f32_16x16x32_bf16(af[mi], bfr[ni], acc[mi][ni], 0, 0, 0);
    }
    __syncthreads();
  }

  // epilogue: bias per ROW (p), no gelu
  char* ep = lds + w*EREG;
  #pragma unroll
  for (int mi = 0; mi < 4; ++mi){
    int rb = (mi << 4) + (lg << 2);
    float4 bq = *(const float4*)(bias + m0 + (wm << 6) + rb);
    #pragma unroll
    for (int ni = 0; ni < 4; ++ni){
      int colw = (ni << 4) + la;
      #pragma unroll
      for (int rg = 0; rg < 4; ++rg){
        float v = acc[mi][ni][rg] + ((const float*)&bq)[rg];
        *(unsigned short*)(ep + (rb + rg)*EPITCH + colw*2) = f2bf(v);
      }
    }
  }
  __syncthreads();

  // coalesced write into t_nat[b][p][c]: row = p (m), col = c (n)
  #pragma unroll
  for (int i = 0; i < 8; ++i){
    int q = (i << 8) + tid;
    int r = q >> 4, ck = q & 15;
    int wreg = ((r >> 6) << 1) | (ck >> 3);
    u16x8 val = *(const u16x8*)(lds + wreg*EREG + (r & 63)*EPITCH + (ck & 7)*16);
    size_t go = ((size_t)bb << 17) + (m0 + r)*512 + c0 + (ck << 3);
    *(u16x8*)(outb + go) = val;
  }
}

extern "C" void kernel_launch(void* const* d_in, const int* in_sizes, int n_in,
                              void* d_out, int out_size, void* d_ws, size_t ws_size,
                              hipStream_t stream) {
  const float* x   = (const float*)d_in[0];
  const float* lng = (const float*)d_in[1];
  const float* lnb = (const float*)d_in[2];
  const float* w1a = (const float*)d_in[3];
  const float* b1a = (const float*)d_in[4];
  const float* w1b = (const float*)d_in[5];
  const float* b1b = (const float*)d_in[6];
  const float* w2a = (const float*)d_in[7];
  const float* b2a = (const float*)d_in[8];
  const float* w2b = (const float*)d_in[9];
  const float* b2b = (const float*)d_in[10];
  float* out = (float*)d_out;
  char* ws = (char*)d_ws;
  unsigned short* bufA = (unsigned short*)ws;                         // 64 MiB
  unsigned short* bufB = (unsigned short*)(ws + (size_t)(64u << 20)); // 64 MiB
  unsigned short* wt1a = (unsigned short*)(ws + (size_t)(128u << 20));
  unsigned short* wt1b = wt1a + 256*256;
  unsigned short* wt2a = wt1b + 256*256;
  unsigned short* wt2b = wt2a + 512*512;
  unsigned short* xb   = (unsigned short*)d_out;  // scratch in d_out (consumed
                                                  // by k_tl2s before final write)

  k_wt4<<<2560, 256, 0, stream>>>(w1a, w1b, w2a, w2b, wt1a, wt1b, wt2a, wt2b);

  // token mixing
  k_ln1x<<<2048, 256, 0, stream>>>(x, lng, lnb, bufA, xb);                          // ht, xb
  k_gemm<256, 4, 0><<<2048, 256, 0, stream>>>(bufA, wt1a, b1a, bufB, nullptr, nullptr); // U
  k_gemmT<<<2048, 256, 0, stream>>>(wt1b, bufB, b1b, bufA);                         // t_nat [b][p][c]

  // residual + LN2 (pure streaming)
  k_tl2s<<<2048, 256, 0, stream>>>(bufA, xb, lng, lnb, bufB);                       // h2

  // channel mixing
  k_gemm<512, 8, 0><<<2048, 256, 0, stream>>>(bufB, wt2a, b2a, bufA, nullptr, nullptr); // u2
  k_gemm<512, 8, 2><<<2048, 256, 0, stream>>>(bufA, wt2b, b2b, nullptr, out, bufB); // out
}

// Round 6
// 271.782 us; speedup vs baseline: 1.8576x; 1.0328x over previous
//
#include <hip/hip_runtime.h>
#include <hip/hip_bf16.h>
#include <math.h>

typedef __bf16 bf16x8 __attribute__((ext_vector_type(8)));
typedef float f32x4 __attribute__((ext_vector_type(4)));
typedef unsigned short u16x8 __attribute__((ext_vector_type(8)));

#define DEV __device__ __forceinline__

DEV unsigned short f2bf(float f){ __hip_bfloat16 h=__float2bfloat16(f); unsigned short u; __builtin_memcpy(&u,&h,2); return u; }
DEV float bf2f(unsigned short u){ __hip_bfloat16 h; __builtin_memcpy(&h,&u,2); return __bfloat162float(h); }

// tanh-form GELU: exp is HW (v_exp_f32), rcp is HW.
DEV float gelu_f(float v){
  float u = v*(0.7978845608f + 0.0356774081f*v*v);
  float e = __expf(2.0f*u);
  float t = 1.0f - 2.0f*__builtin_amdgcn_rcpf(e + 1.0f);
  return 0.5f*v*(1.0f + t);
}

DEV void gl2lds16(const void* g, void* l){
  __builtin_amdgcn_global_load_lds((const __attribute__((address_space(1))) void*)g,
                                   (__attribute__((address_space(3))) void*)l, 16, 0, 0);
}

// ---- tiled weight transpose: WT[n][k] (bf16) = W[k][n] (f32), 64x64 tiles.
// 160 blocks: 16+16 for the 256^2 pair, 64+64 for the 512^2 pair.
__global__ __launch_bounds__(256) void k_wtt(const float* __restrict__ w1a,
                                             const float* __restrict__ w1b,
                                             const float* __restrict__ w2a,
                                             const float* __restrict__ w2b,
                                             unsigned short* __restrict__ o1a,
                                             unsigned short* __restrict__ o1b,
                                             unsigned short* __restrict__ o2a,
                                             unsigned short* __restrict__ o2b){
  __shared__ float tl[64][65];
  int bid = blockIdx.x;
  const float* W; unsigned short* O; int NN, tile_id;
  if (bid < 16)      { W = w1a; O = o1a; NN = 256; tile_id = bid; }
  else if (bid < 32) { W = w1b; O = o1b; NN = 256; tile_id = bid - 16; }
  else if (bid < 96) { W = w2a; O = o2a; NN = 512; tile_id = bid - 32; }
  else               { W = w2b; O = o2b; NN = 512; tile_id = bid - 96; }
  int tpr = NN >> 6;
  int tr = tile_id / tpr, tc = tile_id % tpr;
  int tid = threadIdx.x;
  int r = tid >> 2, cseg = (tid & 3) << 4;
  #pragma unroll
  for (int j = 0; j < 4; ++j){
    float4 v = *(const float4*)(W + (size_t)(tr*64 + r)*NN + tc*64 + cseg + j*4);
    tl[r][cseg + j*4 + 0] = v.x;
    tl[r][cseg + j*4 + 1] = v.y;
    tl[r][cseg + j*4 + 2] = v.z;
    tl[r][cseg + j*4 + 3] = v.w;
  }
  __syncthreads();
  int rn = tid >> 2, kseg = (tid & 3) << 4;
  #pragma unroll
  for (int h = 0; h < 2; ++h){
    u16x8 o;
    #pragma unroll
    for (int j = 0; j < 8; ++j) o[j] = f2bf(tl[kseg + h*8 + j][rn]);
    *(u16x8*)(O + (size_t)(tc*64 + rn)*NN + tr*64 + kseg + h*8) = o;
  }
}

// ---- LN1 + transpose + bf16 x copy (two-phase: all loads hoisted):
// x[b][p][c] f32 -> ht[b][c][p] bf16 (layernormed), xb[b][p][c] bf16 (raw copy)
__global__ __launch_bounds__(256, 4) void k_ln1x(const float* __restrict__ x,
                                                 const float* __restrict__ g,
                                                 const float* __restrict__ be,
                                                 unsigned short* __restrict__ ht,
                                                 unsigned short* __restrict__ xb){
  __shared__ unsigned short tile[32][512];
  int blk = blockIdx.x;
  int b = blk >> 3, p0 = (blk & 7) << 5;
  int tid = threadIdx.x, w = tid >> 6, l = tid & 63;
  float4 gv0 = *(const float4*)(g  + l*8);
  float4 gv1 = *(const float4*)(g  + l*8 + 4);
  float4 bv0 = *(const float4*)(be + l*8);
  float4 bv1 = *(const float4*)(be + l*8 + 4);
  const float* xbase = x + (((size_t)b << 8) + p0) * 512;
  // phase 1: issue all 16 global loads (memory parallelism)
  float4 V0[8], V1[8];
  #pragma unroll
  for (int i = 0; i < 8; ++i){
    int pl = (i << 2) + w;
    const float* row = xbase + (size_t)pl*512 + l*8;
    V0[i] = *(const float4*)row;
    V1[i] = *(const float4*)(row + 4);
  }
  // phase 2: LN + stores
  #pragma unroll
  for (int i = 0; i < 8; ++i){
    int pl = (i << 2) + w;
    float4 v0 = V0[i], v1 = V1[i];
    u16x8 rc;
    rc[0]=f2bf(v0.x); rc[1]=f2bf(v0.y); rc[2]=f2bf(v0.z); rc[3]=f2bf(v0.w);
    rc[4]=f2bf(v1.x); rc[5]=f2bf(v1.y); rc[6]=f2bf(v1.z); rc[7]=f2bf(v1.w);
    *(u16x8*)(xb + (((size_t)b << 8) + p0 + pl)*512 + l*8) = rc;
    float s  = v0.x+v0.y+v0.z+v0.w + v1.x+v1.y+v1.z+v1.w;
    float s2 = v0.x*v0.x+v0.y*v0.y+v0.z*v0.z+v0.w*v0.w
             + v1.x*v1.x+v1.y*v1.y+v1.z*v1.z+v1.w*v1.w;
    #pragma unroll
    for (int off = 32; off; off >>= 1){ s += __shfl_xor(s, off); s2 += __shfl_xor(s2, off); }
    float mu = s * (1.0f/512.0f);
    float rs = rsqrtf(s2*(1.0f/512.0f) - mu*mu + 1e-6f);
    u16x8 o;
    o[0]=f2bf((v0.x-mu)*rs*gv0.x+bv0.x);
    o[1]=f2bf((v0.y-mu)*rs*gv0.y+bv0.y);
    o[2]=f2bf((v0.z-mu)*rs*gv0.z+bv0.z);
    o[3]=f2bf((v0.w-mu)*rs*gv0.w+bv0.w);
    o[4]=f2bf((v1.x-mu)*rs*gv1.x+bv1.x);
    o[5]=f2bf((v1.y-mu)*rs*gv1.y+bv1.y);
    o[6]=f2bf((v1.z-mu)*rs*gv1.z+bv1.z);
    o[7]=f2bf((v1.w-mu)*rs*gv1.w+bv1.w);
    *(u16x8*)(&tile[pl][(l ^ ((pl >> 3) << 1)) << 3]) = o;   // swizzled chunk
  }
  __syncthreads();
  unsigned short* hb = ht + ((size_t)b << 17);   // b * 512 * 256
  #pragma unroll
  for (int it = 0; it < 8; ++it) {
    int c = (it << 6) + (tid >> 2);
    int q = tid & 3, pch = q << 3;
    int cs = c ^ (q << 4);                       // swizzled source column
    u16x8 o;
    #pragma unroll
    for (int j = 0; j < 8; ++j) o[j] = tile[pch + j][cs];
    *(u16x8*)(hb + (size_t)c*256 + p0 + pch) = o;
  }
}

// ---- streaming residual + LN2 (two-phase): h2[r][c] = LN( t[r][c] + xb[r][c] )
__global__ __launch_bounds__(256, 4) void k_tl2s(const unsigned short* __restrict__ t,
                                                 const unsigned short* __restrict__ xb,
                                                 const float* __restrict__ g,
                                                 const float* __restrict__ be,
                                                 unsigned short* __restrict__ h2){
  int tid = threadIdx.x, w = tid >> 6, l = tid & 63;
  float4 gv0 = *(const float4*)(g  + l*8);
  float4 gv1 = *(const float4*)(g  + l*8 + 4);
  float4 bv0 = *(const float4*)(be + l*8);
  float4 bv1 = *(const float4*)(be + l*8 + 4);
  int wid = blockIdx.x*4 + w;                    // 8192 waves, 8 rows each
  // phase 1: issue all 16 loads
  u16x8 T[8], X[8];
  #pragma unroll
  for (int i = 0; i < 8; ++i){
    size_t off = (size_t)(wid + i*8192)*512 + l*8;
    T[i] = *(const u16x8*)(t + off);
    X[i] = *(const u16x8*)(xb + off);
  }
  // phase 2: LN + store
  #pragma unroll
  for (int i = 0; i < 8; ++i){
    float v[8];
    #pragma unroll
    for (int j = 0; j < 8; ++j) v[j] = bf2f(T[i][j]) + bf2f(X[i][j]);
    float s = 0.f, s2 = 0.f;
    #pragma unroll
    for (int j = 0; j < 8; ++j){ s += v[j]; s2 += v[j]*v[j]; }
    #pragma unroll
    for (int off2 = 32; off2; off2 >>= 1){ s += __shfl_xor(s, off2); s2 += __shfl_xor(s2, off2); }
    float mu = s * (1.0f/512.0f);
    float rs = rsqrtf(s2*(1.0f/512.0f) - mu*mu + 1e-6f);
    u16x8 o;
    o[0]=f2bf((v[0]-mu)*rs*gv0.x+bv0.x);
    o[1]=f2bf((v[1]-mu)*rs*gv0.y+bv0.y);
    o[2]=f2bf((v[2]-mu)*rs*gv0.z+bv0.z);
    o[3]=f2bf((v[3]-mu)*rs*gv0.w+bv0.w);
    o[4]=f2bf((v[4]-mu)*rs*gv1.x+bv1.x);
    o[5]=f2bf((v[5]-mu)*rs*gv1.y+bv1.y);
    o[6]=f2bf((v[6]-mu)*rs*gv1.z+bv1.z);
    o[7]=f2bf((v[7]-mu)*rs*gv1.w+bv1.w);
    *(u16x8*)(h2 + (size_t)(wid + i*8192)*512 + l*8) = o;
  }
}

// ---- m97-style 128x128 GEMM, C[m][n] = epi(sum_k A[m][k]*BT[n][k] + bias[n])
// MODE 0: outb = bf16(gelu(v))   MODE 1: outb = bf16(v)
// MODE 2: outf = f32(v) + f32(res[m][n])
template<int N, int KT, int MODE>
__global__ __launch_bounds__(256, 2) void k_gemm(
    const unsigned short* __restrict__ A,
    const unsigned short* __restrict__ BT,
    const float* __restrict__ bias,
    unsigned short* __restrict__ outb,
    float* __restrict__ outf,
    const unsigned short* __restrict__ res)
{
  constexpr int K = KT*64;
  constexpr int nTn = N/128;
  constexpr int EPITCH = 176;
  constexpr int EREG   = 64*EPITCH;
  __shared__ char lds[4*EREG];
  char* lsA = lds;
  char* lsB = lds + 16384;

  int nwg = gridDim.x, bid = blockIdx.x;
  int wgid = ((nwg & 7) == 0) ? ((bid & 7)*(nwg >> 3) + (bid >> 3)) : bid;
  int tm = wgid / nTn, tn = wgid % nTn;
  size_t m0 = (size_t)tm * 128;
  int n0 = tn * 128;

  const int tid = threadIdx.x;
  const int w = tid >> 6, l = tid & 63;
  const int wm = w >> 1, wn = w & 1;
  const int la = l & 15, lg = l >> 4;

  f32x4 acc[4][4];
  #pragma unroll
  for (int i = 0; i < 4; ++i)
    #pragma unroll
    for (int j = 0; j < 4; ++j) acc[i][j] = (f32x4){0.f,0.f,0.f,0.f};

  for (int kt = 0; kt < KT; ++kt){
    int kb = kt << 6;
    #pragma unroll
    for (int i = 0; i < 4; ++i){
      int q = (i << 8) + tid;
      int row = q >> 3, sc = q & 7;
      int cc = sc ^ (row & 7);
      gl2lds16(A  + (m0 + row)*K + kb + (cc << 3), lsA + q*16);
      gl2lds16(BT + (size_t)(n0 + row)*K + kb + (cc << 3), lsB + q*16);
    }
    __syncthreads();
    #pragma unroll
    for (int ks = 0; ks < 2; ++ks){
      int c = (ks << 2) + lg;
      bf16x8 af[4], bfr[4];
      #pragma unroll
      for (int mi = 0; mi < 4; ++mi){
        int rr = (wm << 6) + (mi << 4) + la;
        af[mi] = *(const bf16x8*)(lsA + ((rr << 3) + (c ^ (rr & 7)))*16);
      }
      #pragma unroll
      for (int ni = 0; ni < 4; ++ni){
        int rn = (wn << 6) + (ni << 4) + la;
        bfr[ni] = *(const bf16x8*)(lsB + ((rn << 3) + (c ^ (rn & 7)))*16);
      }
      #pragma unroll
      for (int mi = 0; mi < 4; ++mi)
        #pragma unroll
        for (int ni = 0; ni < 4; ++ni)
          acc[mi][ni] = __builtin_amdgcn_mfma_f32_16x16x32_bf16(af[mi], bfr[ni], acc[mi][ni], 0, 0, 0);
    }
    __syncthreads();
  }

  char* ep = lds + w*EREG;
  #pragma unroll
  for (int ni = 0; ni < 4; ++ni){
    int colw = (ni << 4) + la;
    float bv = bias[n0 + (wn << 6) + colw];
    #pragma unroll
    for (int mi = 0; mi < 4; ++mi){
      #pragma unroll
      for (int rg = 0; rg < 4; ++rg){
        float v = acc[mi][ni][rg] + bv;
        if (MODE == 0) v = gelu_f(v);
        int r = (mi << 4) + (lg << 2) + rg;
        *(unsigned short*)(ep + r*EPITCH + colw*2) = f2bf(v);
      }
    }
  }
  __syncthreads();

  #pragma unroll
  for (int i = 0; i < 8; ++i){
    int q = (i << 8) + tid;
    int r = q >> 4, ck = q & 15;
    int wreg = ((r >> 6) << 1) | (ck >> 3);
    u16x8 val = *(const u16x8*)(lds + wreg*EREG + (r & 63)*EPITCH + (ck & 7)*16);
    size_t go = (m0 + r)*N + n0 + (ck << 3);
    if (MODE != 2){
      *(u16x8*)(outb + go) = val;
    } else {
      u16x8 rv = *(const u16x8*)(res + go);
      float4 o0, o1;
      o0.x = bf2f(val[0]) + bf2f(rv[0]);
      o0.y = bf2f(val[1]) + bf2f(rv[1]);
      o0.z = bf2f(val[2]) + bf2f(rv[2]);
      o0.w = bf2f(val[3]) + bf2f(rv[3]);
      o1.x = bf2f(val[4]) + bf2f(rv[4]);
      o1.y = bf2f(val[5]) + bf2f(rv[5]);
      o1.z = bf2f(val[6]) + bf2f(rv[6]);
      o1.w = bf2f(val[7]) + bf2f(rv[7]);
      *(float4*)(outf + go)     = o0;
      *(float4*)(outf + go + 4) = o1;
    }
  }
}

// ---- token G2, transposed-output: t_nat[b][p][c] = sum_k wt1b[p][k]*U[(b,c)][k] + b1b[p]
__global__ __launch_bounds__(256, 2) void k_gemmT(
    const unsigned short* __restrict__ A,
    const unsigned short* __restrict__ BT,
    const float* __restrict__ bias,
    unsigned short* __restrict__ outb)
{
  constexpr int K = 256, KT = 4;
  constexpr int EPITCH = 176;
  constexpr int EREG   = 64*EPITCH;
  __shared__ char lds[4*EREG];
  char* lsA = lds;
  char* lsB = lds + 16384;

  int nwg = gridDim.x, bid = blockIdx.x;
  int wgid = (bid & 7)*(nwg >> 3) + (bid >> 3);
  int tm = wgid & 1, tn = wgid >> 1;
  size_t m0 = (size_t)tm * 128;
  int n0 = tn * 128;
  int bb = n0 >> 9, c0 = n0 & 511;

  const int tid = threadIdx.x;
  const int w = tid >> 6, l = tid & 63;
  const int wm = w >> 1, wn = w & 1;
  const int la = l & 15, lg = l >> 4;

  f32x4 acc[4][4];
  #pragma unroll
  for (int i = 0; i < 4; ++i)
    #pragma unroll
    for (int j = 0; j < 4; ++j) acc[i][j] = (f32x4){0.f,0.f,0.f,0.f};

  for (int kt = 0; kt < KT; ++kt){
    int kb = kt << 6;
    #pragma unroll
    for (int i = 0; i < 4; ++i){
      int q = (i << 8) + tid;
      int row = q >> 3, sc = q & 7;
      int cc = sc ^ (row & 7);
      gl2lds16(A  + (m0 + row)*K + kb + (cc << 3), lsA + q*16);
      gl2lds16(BT + (size_t)(n0 + row)*K + kb + (cc << 3), lsB + q*16);
    }
    __syncthreads();
    #pragma unroll
    for (int ks = 0; ks < 2; ++ks){
      int c = (ks << 2) + lg;
      bf16x8 af[4], bfr[4];
      #pragma unroll
      for (int mi = 0; mi < 4; ++mi){
        int rr = (wm << 6) + (mi << 4) + la;
        af[mi] = *(const bf16x8*)(lsA + ((rr << 3) + (c ^ (rr & 7)))*16);
      }
      #pragma unroll
      for (int ni = 0; ni < 4; ++ni){
        int rn = (wn << 6) + (ni << 4) + la;
        bfr[ni] = *(const bf16x8*)(lsB + ((rn << 3) + (c ^ (rn & 7)))*16);
      }
      #pragma unroll
      for (int mi = 0; mi < 4; ++mi)
        #pragma unroll
        for (int ni = 0; ni < 4; ++ni)
          acc[mi][ni] = __builtin_amdgcn_mfma_f32_16x16x32_bf16(af[mi], bfr[ni], acc[mi][ni], 0, 0, 0);
    }
    __syncthreads();
  }

  char* ep = lds + w*EREG;
  #pragma unroll
  for (int mi = 0; mi < 4; ++mi){
    int rb = (mi << 4) + (lg << 2);
    float4 bq = *(const float4*)(bias + m0 + (wm << 6) + rb);
    #pragma unroll
    for (int ni = 0; ni < 4; ++ni){
      int colw = (ni << 4) + la;
      #pragma unroll
      for (int rg = 0; rg < 4; ++rg){
        float v = acc[mi][ni][rg] + ((const float*)&bq)[rg];
        *(unsigned short*)(ep + (rb + rg)*EPITCH + colw*2) = f2bf(v);
      }
    }
  }
  __syncthreads();

  #pragma unroll
  for (int i = 0; i < 8; ++i){
    int q = (i << 8) + tid;
    int r = q >> 4, ck = q & 15;
    int wreg = ((r >> 6) << 1) | (ck >> 3);
    u16x8 val = *(const u16x8*)(lds + wreg*EREG + (r & 63)*EPITCH + (ck & 7)*16);
    size_t go = ((size_t)bb << 17) + (m0 + r)*512 + c0 + (ck << 3);
    *(u16x8*)(outb + go) = val;
  }
}

extern "C" void kernel_launch(void* const* d_in, const int* in_sizes, int n_in,
                              void* d_out, int out_size, void* d_ws, size_t ws_size,
                              hipStream_t stream) {
  const float* x   = (const float*)d_in[0];
  const float* lng = (const float*)d_in[1];
  const float* lnb = (const float*)d_in[2];
  const float* w1a = (const float*)d_in[3];
  const float* b1a = (const float*)d_in[4];
  const float* w1b = (const float*)d_in[5];
  const float* b1b = (const float*)d_in[6];
  const float* w2a = (const float*)d_in[7];
  const float* b2a = (const float*)d_in[8];
  const float* w2b = (const float*)d_in[9];
  const float* b2b = (const float*)d_in[10];
  float* out = (float*)d_out;
  char* ws = (char*)d_ws;
  unsigned short* bufA = (unsigned short*)ws;                         // 64 MiB
  unsigned short* bufB = (unsigned short*)(ws + (size_t)(64u << 20)); // 64 MiB
  unsigned short* wt1a = (unsigned short*)(ws + (size_t)(128u << 20));
  unsigned short* wt1b = wt1a + 256*256;
  unsigned short* wt2a = wt1b + 256*256;
  unsigned short* wt2b = wt2a + 512*512;
  unsigned short* xb   = (unsigned short*)d_out;  // scratch in d_out (consumed
                                                  // by k_tl2s before final write)

  k_wtt<<<160, 256, 0, stream>>>(w1a, w1b, w2a, w2b, wt1a, wt1b, wt2a, wt2b);

  // token mixing
  k_ln1x<<<2048, 256, 0, stream>>>(x, lng, lnb, bufA, xb);                          // ht, xb
  k_gemm<256, 4, 0><<<2048, 256, 0, stream>>>(bufA, wt1a, b1a, bufB, nullptr, nullptr); // U
  k_gemmT<<<2048, 256, 0, stream>>>(wt1b, bufB, b1b, bufA);                         // t_nat [b][p][c]

  // residual + LN2 (pure streaming)
  k_tl2s<<<2048, 256, 0, stream>>>(bufA, xb, lng, lnb, bufB);                       // h2

  // channel mixing
  k_gemm<512, 8, 0><<<2048, 256, 0, stream>>>(bufB, wt2a, b2a, bufA, nullptr, nullptr); // u2
  k_gemm<512, 8, 2><<<2048, 256, 0, stream>>>(bufA, wt2b, b2b, nullptr, out, bufB); // out
}